// Round 12
// baseline (87.841 us; speedup 1.0000x reference)
//
#include <hip/hip_runtime.h>
#include <hip/hip_bf16.h>
#include <stdint.h>
#include <math.h>

// TernaryMobiusLinear: out = mobius( (x @ W) * scale ), x 8192x2048 fp32, W ternary.
// Path: x -> i8 per-row quant; W -> i8 exact; 16x16x64 i8 MFMA GEMM (i32 exact),
// 128^2 tile / BKB=64 / 48KB LDS TRIPLE-buffer / counted vmcnt (T4); bf16 C; Mobius.
#define M_DIM 8192
#define K_DIM 2048
#define N_DIM 2048

#define BM 128
#define BN 128
#define BKB 64             // K-tile bytes; row = 64 B = 4 x 16B chunks
#define NT (K_DIM / BKB)   // 32

typedef __attribute__((ext_vector_type(4))) int int32x4;
typedef __attribute__((ext_vector_type(4))) float float4v;

__device__ __forceinline__ ushort f2bf(float f) {
    uint32_t u = __builtin_bit_cast(uint32_t, f);
    u = (u + 0x7fffu + ((u >> 16) & 1u)) >> 16;
    return (ushort)u;
}

#define GLD16(gp, lp)                                                          \
    __builtin_amdgcn_global_load_lds(                                          \
        (const __attribute__((address_space(1))) void*)(gp),                   \
        (__attribute__((address_space(3))) void*)(lp), 16, 0, 0)

#define BAR()                                                                  \
    do {                                                                       \
        asm volatile("" ::: "memory");                                         \
        __builtin_amdgcn_s_barrier();                                          \
        asm volatile("" ::: "memory");                                         \
    } while (0)

#define VMCNT(n) asm volatile("s_waitcnt vmcnt(" #n ")" ::: "memory")

// ---------------- prepass 1: W (K x N fp32 ternary) -> Wq (N x K i8, transposed) ----------
__global__ __launch_bounds__(256) void transpose_w_i8(const float* __restrict__ W,
                                                      signed char* __restrict__ Wq) {
    __shared__ float tile[32][33];
    const int tb = blockIdx.x;
    const int kb = (tb & 63) * 32;
    const int nb = (tb >> 6) * 32;
    const int tx = threadIdx.x & 31;
    const int ty4 = (threadIdx.x >> 5) * 4;
#pragma unroll
    for (int i = 0; i < 4; i++)
        tile[ty4 + i][tx] = W[(size_t)(kb + ty4 + i) * N_DIM + nb + tx];
    __syncthreads();
    const int r = threadIdx.x >> 3;
    const int c4 = threadIdx.x & 7;
    uint32_t pk = 0;
#pragma unroll
    for (int j = 0; j < 4; j++) {
        const int q = (int)tile[c4 * 4 + j][r];
        pk |= (uint32_t)(q & 255) << (8 * j);
    }
    *(uint32_t*)&Wq[(size_t)(nb + r) * K_DIM + kb + c4 * 4] = pk;
}

// ---------------- prepass 2: x fp32 -> i8 with per-row scale ----------------
__global__ __launch_bounds__(256) void quant_x(const float* __restrict__ X,
                                               signed char* __restrict__ Xq,
                                               float* __restrict__ srow) {
    const int row = blockIdx.x;
    const int t = threadIdx.x;
    const float* p = X + (size_t)row * K_DIM;
    float4v a = *(const float4v*)&p[t * 8];
    float4v b = *(const float4v*)&p[t * 8 + 4];
    float m = 0.f;
#pragma unroll
    for (int j = 0; j < 4; j++) m = fmaxf(m, fmaxf(fabsf(a[j]), fabsf(b[j])));
#pragma unroll
    for (int off = 1; off < 64; off <<= 1) m = fmaxf(m, __shfl_xor(m, off));
    __shared__ float wm[4];
    if ((t & 63) == 0) wm[t >> 6] = m;
    __syncthreads();
    float bm = fmaxf(fmaxf(wm[0], wm[1]), fmaxf(wm[2], wm[3]));
    bm = fmaxf(bm, 1e-8f);
    const float inv = 127.f / bm;
    uint32_t lo = 0, hi = 0;
#pragma unroll
    for (int j = 0; j < 4; j++) {
        const int qa = __float2int_rn(a[j] * inv);
        const int qb = __float2int_rn(b[j] * inv);
        lo |= (uint32_t)(qa & 255) << (8 * j);
        hi |= (uint32_t)(qb & 255) << (8 * j);
    }
    uint32_t* q = (uint32_t*)&Xq[(size_t)row * K_DIM + t * 8];
    q[0] = lo;
    q[1] = hi;
    if (t == 0) srow[row] = bm / 127.f;
}

// ---------------- GEMM: Cb = bf16( (Xq @ Wq^T) * scale ), i32 accum exact ----------------
// 128x128 tile, BKB=64, 4 waves (2M x 2N), per-wave C = 64x64 = 4x4 frags of 16x16.
// TRIPLE-buffered LDS (48KB): A bufs @0/4096/8192, B bufs @12288/16384/20480 (ushort).
// T4 counted-vmcnt pipeline:
//   tile-t top (post-BAR, reads[t-1] certified): issue stage[t+2] into buf (t+2)%3
//     (= buf (t-1)%3, free by certification);
//   compute tile t from buf t%3 (certified at tile t-1 end);
//   tile end: VMCNT(4) — leaves stage[t+2]'s 4 per-wave loads IN FLIGHT, certifies
//     stage[t+1]; BAR propagates certification to all waves. Drain hits 0 only at
//     the last two tiles. In-flight window per load = 2 tiles of work (covers HBM/L3).
__global__ __launch_bounds__(256, 3) void gemm_i8(const signed char* __restrict__ Xq,
                                                  const signed char* __restrict__ Wq,
                                                  const float* __restrict__ scale,
                                                  ushort* __restrict__ Cb) {
    __shared__ __align__(16) ushort lds[24576];   // 48 KiB

    const int tid = threadIdx.x;
    const int w = tid >> 6;            // wave 0..3
    const int lane = tid & 63;
    const int lrow = lane & 15;
    const int khi3 = lane >> 4;        // 0..3 = k-chunk of the 64B row
    const int rswz = (lrow & 3) ^ (lrow >> 2);   // swz(r): 2-way banks (free, m136)

    // XCD-chunked bijective swizzle: 1024 blocks, 8 XCDs, q=128
    const int bid = blockIdx.x;
    const int wg = (bid & 7) * 128 + (bid >> 3);
    const int mt = wg >> 4;            // 0..63
    const int nt = wg & 15;            // 0..15
    const int row0 = mt * BM;
    const int col0 = nt * BN;

    const int wr = (w >> 1) * 64;
    const int wc = (w & 1) * 64;

    // staging: 512 chunks per matrix per tile; thread covers s = (i*4+w)*64+lane, i=0,1
    int r_[2], cs_[2];
#pragma unroll
    for (int i = 0; i < 2; ++i) {
        const int s = (i * 4 + w) * 64 + lane;
        const int r = s >> 2;
        r_[i] = r;
        cs_[i] = (s & 3) ^ ((r & 3) ^ ((r >> 2) & 3));   // pre-swizzled source chunk
    }

    // stage one matrix tile (8KB) into ldsbase (ushort units); kbyte = t*BKB
    auto stageM = [&](const signed char* srcbase, int kbyte, int ldsbase) {
#pragma unroll
        for (int i = 0; i < 2; ++i) {
            GLD16(srcbase + (size_t)r_[i] * K_DIM + kbyte + cs_[i] * 16,
                  lds + ldsbase + (i * 4 + w) * 512);
        }
    };

// read frag: row = q*16 + lrow, chunk = khi3 ^ rswz; 32 ushorts/row, 8/chunk
#define RD(base, q) (*(const int32x4*)&lds[(base) + ((q) * 16 + lrow) * 32 + ((khi3 ^ rswz) * 8)])

    int32x4 acc[4][4] = {};

    const signed char* Asrc = Xq + (size_t)row0 * K_DIM;
    const signed char* Bsrc = Wq + (size_t)col0 * K_DIM;

    // prologue: stage tiles 0,1 into bufs 0,1; certify tile 0 (counted: leave stage[1])
    stageM(Asrc, 0, 0);
    stageM(Bsrc, 0, 12288);
    stageM(Asrc, BKB, 4096);
    stageM(Bsrc, BKB, 12288 + 4096);
    VMCNT(4);
    BAR();

    for (int t = 0; t < NT; ++t) {
        const int buf = t % 3;
        const int abase = buf * 4096;
        const int bbase = 12288 + buf * 4096;

        // issue stage[t+2] into buf (t+2)%3 (freed by this tile-top barrier)
        if (t + 2 < NT) {
            const int nb = (t + 2) % 3;
            stageM(Asrc, (t + 2) * BKB, nb * 4096);
            stageM(Bsrc, (t + 2) * BKB, 12288 + nb * 4096);
        }

        // free-run compute: 8 ds_read_b128 + 16 MFMA
        int32x4 af[4], bf[4];
#pragma unroll
        for (int n = 0; n < 4; ++n) bf[n] = RD(bbase + wc * 32, n);
#pragma unroll
        for (int m = 0; m < 4; ++m) af[m] = RD(abase + wr * 32, m);
        __builtin_amdgcn_s_setprio(1);
#pragma unroll
        for (int m = 0; m < 4; ++m)
#pragma unroll
            for (int n = 0; n < 4; ++n)
                acc[m][n] = __builtin_amdgcn_mfma_i32_16x16x64_i8(af[m], bf[n], acc[m][n], 0, 0, 0);
        __builtin_amdgcn_s_setprio(0);

        // tile end: certify stage[t+1], keep stage[t+2] in flight (T4)
        if (t < NT - 2) { VMCNT(4); } else { VMCNT(0); }
        BAR();
    }

    // epilogue: Cb = bf16( acc * scale[col] )  (16x16 C/D: col=lane&15, row=(lane>>4)*4+j)
    const int crow0 = row0 + wr + khi3 * 4;
    const int ccol = col0 + wc + lrow;
#pragma unroll
    for (int n = 0; n < 4; ++n) {
        const float sc = scale[ccol + n * 16];
#pragma unroll
        for (int m = 0; m < 4; ++m) {
#pragma unroll
            for (int j = 0; j < 4; ++j) {
                const float v = (float)acc[m][n][j] * sc;
                Cb[(size_t)(crow0 + m * 16 + j) * N_DIM + ccol + n * 16] = f2bf(v);
            }
        }
    }
#undef RD
}

// ---------------- Mobius epilogue: out = srow * Cb * gain(norm(srow*Cb)) ----------------
__global__ __launch_bounds__(256) void mobius_bf16(const ushort* __restrict__ Cb,
                                                   const float* __restrict__ srow,
                                                   float* __restrict__ out) {
    const int row = blockIdx.x;
    const ushort* p = Cb + (size_t)row * N_DIM;
    float* q = out + (size_t)row * N_DIM;
    const int t = threadIdx.x;
    const float s = srow[row];

    typedef __attribute__((ext_vector_type(8))) short short8;
    short8 v = *(const short8*)&p[t * 8];
    float f[8];
#pragma unroll
    for (int j = 0; j < 8; ++j) {
        const uint32_t u = ((uint32_t)(uint16_t)v[j]) << 16;
        f[j] = __builtin_bit_cast(float, u);
    }
    float ss = 0.f;
#pragma unroll
    for (int j = 0; j < 8; ++j) ss += f[j] * f[j];
#pragma unroll
    for (int off = 1; off < 64; off <<= 1) ss += __shfl_xor(ss, off);
    __shared__ float wsum[4];
    if ((t & 63) == 0) wsum[t >> 6] = ss;
    __syncthreads();
    const float tot = (wsum[0] + wsum[1] + wsum[2] + wsum[3]) * s * s;
    const float vn = fmaxf(sqrtf(tot), 1e-7f);
    const float tf = tanhf(vn) / (vn + 1e-7f);
    const float on = fmaxf(tf * vn, 1e-7f);
    const float g = s * tf * fminf(0.99f / on, 1.0f);
    float4v o0, o1;
#pragma unroll
    for (int j = 0; j < 4; ++j) { o0[j] = f[j] * g; o1[j] = f[4 + j] * g; }
    *(float4v*)&q[t * 8] = o0;
    *(float4v*)&q[t * 8 + 4] = o1;
}

extern "C" void kernel_launch(void* const* d_in, const int* in_sizes, int n_in,
                              void* d_out, int out_size, void* d_ws, size_t ws_size,
                              hipStream_t stream) {
    const float* x = (const float*)d_in[0];
    const float* w = (const float*)d_in[1];
    const float* scale = (const float*)d_in[2];
    float* out = (float*)d_out;

    // ws layout: Wq @0 (4 MB), Xq @4M (16 MB), srow @20971520 (32 KB), Cb @21037056 (32 MB)
    signed char* Wq = (signed char*)d_ws;
    signed char* Xq = (signed char*)d_ws + 4194304;
    float* srow = (float*)((char*)d_ws + 20971520);
    ushort* Cb = (ushort*)((char*)d_ws + 21037056);

    transpose_w_i8<<<dim3(64 * 64), dim3(256), 0, stream>>>(w, Wq);
    quant_x<<<dim3(M_DIM), dim3(256), 0, stream>>>(x, Xq, srow);
    gemm_i8<<<dim3((M_DIM / BM) * (N_DIM / BN)), dim3(256), 0, stream>>>(Xq, Wq, scale, Cb);
    mobius_bf16<<<dim3(M_DIM), dim3(256), 0, stream>>>(Cb, srow, out);
}